// Round 6
// baseline (206.577 us; speedup 1.0000x reference)
//
#include <hip/hip_runtime.h>
#include <stdint.h>

typedef unsigned long long ull;

#define Bdim 64
#define Tdim 8192
#define MAXP 32
#define NW (Tdim / 64)        // 128 bitmask words per row
#define VOCAB_WORDS_MAX 1024  // >= ceil(50257/64) = 786

// ---------------------------------------------------------------------------
// Kernel 1: fused layout-detect + bitmask pack (single block).
// int32 layout: every 32-bit word is 0 or 1. uint8 layout: 4 bools/word ->
// with ~3000 random set bits, some word has a byte>0 above byte0 => word>1.
// ---------------------------------------------------------------------------
__global__ __launch_bounds__(1024) void pack_tables_kernel(
    const void* __restrict__ punct,
    const void* __restrict__ abbr,
    int vocab,
    ull* __restrict__ pbits,
    ull* __restrict__ abits) {
    __shared__ int s_flag;
    if (threadIdx.x == 0) s_flag = 0;
    __syncthreads();

    const unsigned* p32 = (const unsigned*)punct;
    const int nw32 = vocab >> 2;
    int m = 0;
    for (int i = threadIdx.x; i < nw32; i += 1024) {
        if (p32[i] > 1u) m = 1;
    }
    if (m) atomicOr(&s_flag, 1);
    __syncthreads();
    const bool u8 = (s_flag != 0);

    const int nwords = (vocab + 63) >> 6;
    for (int w = threadIdx.x; w < nwords; w += 1024) {
        ull pw = 0ull, aw = 0ull;
        const int base = w << 6;
#pragma unroll 1
        for (int j = 0; j < 64; ++j) {
            int tok = base + j;
            if (tok >= vocab) break;
            bool pv, av;
            if (u8) {
                pv = ((const uint8_t*)punct)[tok] != 0;
                av = ((const uint8_t*)abbr)[tok] != 0;
            } else {
                pv = ((const int*)punct)[tok] != 0;
                av = ((const int*)abbr)[tok] != 0;
            }
            if (pv) pw |= 1ull << j;
            if (av) aw |= 1ull << j;
        }
        pbits[w] = pw;
        abits[w] = aw;
    }
}

// ---------------------------------------------------------------------------
// Kernel A: one block per row, fully parallel boundary determination.
//   boundary(t) = t<=LR && (base_end(t) || t==LR || (t - prev_anchor)%32==0)
// Word-level prefixes (prev-anchor max-scan, popcount sum-scan, prev-boundary
// max-scan) are computed by wave 0 with shfl scans (no serial loops).
// ---------------------------------------------------------------------------
__global__ __launch_bounds__(1024) void phrase_meta_kernel(
    const int* __restrict__ ids,
    const ull* __restrict__ pbits,
    const ull* __restrict__ abits,
    int* __restrict__ out_end,          // [B, T]
    int* __restrict__ out_pid,          // [B, T]
    unsigned int* __restrict__ ws_nb,   // [B]
    unsigned int* __restrict__ ws_info) // [B, T]: first | (end<<16)
{
    __shared__ ull base_bits[NW];
    __shared__ ull end_bits[NW];
    __shared__ int A_pref[NW];   // last base-anchor pos in words < w, or -1
    __shared__ int wpre[NW];     // # end bits in words < w
    __shared__ int E_pref[NW];   // last end-boundary pos in words < w, or -1
    __shared__ int s_last;

    const int b = blockIdx.x;
    const int tid = threadIdx.x;
    const int lane = tid & 63;
    const int wv = tid >> 6;                 // 0..15
    const int* __restrict__ row = ids + (size_t)b * Tdim;
    const size_t rowbase = (size_t)b * Tdim;

    if (tid == 0) s_last = -1;
    __syncthreads();

    // ---- Phase 1: base_end bits (ballot), last_real, out_end = -1 fill ----
    int lmax = -1;
#pragma unroll
    for (int k = 0; k < Tdim / 1024; ++k) {
        int t = k * 1024 + tid;
        int id = row[t];
        bool real = (id != 0);
        bool pu = (pbits[id >> 6] >> (id & 63)) & 1ull;
        bool ab = false;
        if (t > 0) {
            int pv = row[t - 1];
            ab = (abits[pv >> 6] >> (pv & 63)) & 1ull;
        }
        bool be = pu && !ab && real;
        ull bal = __ballot(be);
        if (lane == 0) base_bits[k * 16 + wv] = bal;
        if (real) lmax = t;
        out_end[rowbase + t] = -1;
    }
    for (int off = 32; off; off >>= 1) {
        int o = __shfl_down(lmax, off);
        lmax = o > lmax ? o : lmax;
    }
    if (lane == 0) atomicMax(&s_last, lmax);
    __syncthreads();

    // ---- Scan 1 (wave 0): exclusive max-scan of last-anchor position ----
    if (tid < 64) {
        int w0 = tid * 2, w1 = w0 + 1;
        ull x0 = base_bits[w0], x1 = base_bits[w1];
        int h0 = x0 ? (w0 << 6) + 63 - __builtin_clzll(x0) : -1;
        int h1 = x1 ? (w1 << 6) + 63 - __builtin_clzll(x1) : -1;
        int inc = h1 > h0 ? h1 : h0;
#pragma unroll
        for (int off = 1; off < 64; off <<= 1) {
            int o = __shfl_up(inc, off);
            if (tid >= off && o > inc) inc = o;
        }
        int exc = __shfl_up(inc, 1);
        if (tid == 0) exc = -1;
        A_pref[w0] = exc;
        A_pref[w1] = h0 > exc ? h0 : exc;
    }
    __syncthreads();

    // ---- Phase 2: boundary bits (ballot) ----
    const int LR = s_last;
#pragma unroll
    for (int k = 0; k < Tdim / 1024; ++k) {
        int t = k * 1024 + tid;
        int w = k * 16 + wv;
        ull bw = base_bits[w];
        ull below = bw & ((1ull << lane) - 1ull);
        int pa = below ? ((w << 6) + 63 - __builtin_clzll(below)) : A_pref[w];
        bool bnd = (t <= LR) &&
                   (((bw >> lane) & 1ull) || (t == LR) || (((t - pa) & 31) == 0));
        ull bal = __ballot(bnd);
        if (lane == 0) end_bits[w] = bal;
    }
    __syncthreads();

    // ---- Scan 2 (wave 0): popcount sum-scan + prev-boundary max-scan ----
    if (tid < 64) {
        int w0 = tid * 2, w1 = w0 + 1;
        ull x0 = end_bits[w0], x1 = end_bits[w1];
        int c0 = __builtin_popcountll(x0);
        int csum = c0 + __builtin_popcountll(x1);
        int h0 = x0 ? (w0 << 6) + 63 - __builtin_clzll(x0) : -1;
        int h1 = x1 ? (w1 << 6) + 63 - __builtin_clzll(x1) : -1;
        int incC = csum;
        int incH = h1 > h0 ? h1 : h0;
#pragma unroll
        for (int off = 1; off < 64; off <<= 1) {
            int oC = __shfl_up(incC, off);
            int oH = __shfl_up(incH, off);
            if (tid >= off) {
                incC += oC;
                if (oH > incH) incH = oH;
            }
        }
        int excC = __shfl_up(incC, 1);
        int excH = __shfl_up(incH, 1);
        if (tid == 0) { excC = 0; excH = -1; }
        wpre[w0] = excC;
        wpre[w1] = excC + c0;
        E_pref[w0] = excH;
        E_pref[w1] = h0 > excH ? h0 : excH;
        if (tid == 63) ws_nb[b] = (unsigned int)incC;
    }
    __syncthreads();

    // ---- Phase 3: out_pid, per-phrase metadata, out_end overwrite ----
#pragma unroll
    for (int k = 0; k < Tdim / 1024; ++k) {
        int t = k * 1024 + tid;
        int w = k * 16 + wv;
        ull ew = end_bits[w];
        ull below = ew & ((1ull << lane) - 1ull);
        int pid = wpre[w] + __builtin_popcountll(below);
        out_pid[rowbase + t] = pid;
        if ((ew >> lane) & 1ull) {
            int pe = below ? ((w << 6) + 63 - __builtin_clzll(below)) : E_pref[w];
            int first = pe + 1;
            ws_info[(size_t)b * Tdim + pid] =
                (unsigned int)first | ((unsigned int)t << 16);
            out_end[rowbase + pid] = t;
        }
    }
}

// ---------------------------------------------------------------------------
// Kernel B: dense coalesced fill of mask + token_idx (final values everywhere;
// replaces memset). 2048 blocks x 256 threads, int4 stores.
// ---------------------------------------------------------------------------
__global__ __launch_bounds__(256) void fill_outputs_kernel(
    const unsigned int* __restrict__ ws_nb,
    const unsigned int* __restrict__ ws_info,
    int4* __restrict__ m4,    // [B * 65536] int4 view of [B,T,32] mask
    int4* __restrict__ i4)    // [B * 65536] int4 view of [B,T,32] idx
{
    const int row = blockIdx.x >> 5;       // 32 blocks per row
    const int seg = blockIdx.x & 31;
    const int nb = (int)ws_nb[row];
    const unsigned int* __restrict__ info = ws_info + (size_t)row * Tdim;
    int4* __restrict__ mrow = m4 + (size_t)row * 65536;
    int4* __restrict__ irow = i4 + (size_t)row * 65536;
#pragma unroll
    for (int i = 0; i < 8; ++i) {
        int g = seg * 2048 + i * 256 + (int)threadIdx.x;  // int4 index in row
        int pid = g >> 3;
        int s0 = (g & 7) << 2;
        int4 mv = {0, 0, 0, 0};
        int4 iv = {0, 0, 0, 0};
        if (pid < nb) {
            unsigned int u = info[pid];
            int first = (int)(u & 0xFFFFu);
            int len = (int)(u >> 16) - first + 1;
            mv.x = (s0 + 0) < len;
            mv.y = (s0 + 1) < len;
            mv.z = (s0 + 2) < len;
            mv.w = (s0 + 3) < len;
            iv.x = (s0 + 0) < len ? first + s0 + 0 : 0;
            iv.y = (s0 + 1) < len ? first + s0 + 1 : 0;
            iv.z = (s0 + 2) < len ? first + s0 + 2 : 0;
            iv.w = (s0 + 3) < len ? first + s0 + 3 : 0;
        }
        mrow[g] = mv;
        irow[g] = iv;
    }
}

// ---------------------------------------------------------------------------
extern "C" void kernel_launch(void* const* d_in, const int* in_sizes, int n_in,
                              void* d_out, int out_size, void* d_ws, size_t ws_size,
                              hipStream_t stream) {
    const int* ids = (const int*)d_in[0];
    const void* punct = d_in[1];
    const void* abbr = d_in[2];
    const int vocab = in_sizes[1];

    int* out = (int*)d_out;
    const size_t maskN = (size_t)Bdim * Tdim * MAXP;   // 16,777,216
    int* out_mask = out;
    int* out_idx  = out + maskN;
    int* out_end  = out + 2 * maskN;
    int* out_pid  = out + 2 * maskN + (size_t)Bdim * Tdim;

    // ws layout: pbits(8KB) | abits(8KB) | nb(256B) | info(2MB)
    ull* pbits = (ull*)d_ws;
    ull* abits = pbits + VOCAB_WORDS_MAX;
    unsigned int* ws_nb   = (unsigned int*)(abits + VOCAB_WORDS_MAX);
    unsigned int* ws_info = ws_nb + 64;   // B*T uints = 2 MB

    pack_tables_kernel<<<1, 1024, 0, stream>>>(punct, abbr, vocab, pbits, abits);

    phrase_meta_kernel<<<Bdim, 1024, 0, stream>>>(
        ids, pbits, abits, out_end, out_pid, ws_nb, ws_info);

    fill_outputs_kernel<<<Bdim * 32, 256, 0, stream>>>(
        ws_nb, ws_info, (int4*)out_mask, (int4*)out_idx);
}